// Round 5
// baseline (110.217 us; speedup 1.0000x reference)
//
#include <hip/hip_runtime.h>
#include <hip/hip_bf16.h>

#define N_NODES 100000
#define N_EDGES 1250000
#define DIM 64
#define NB 782            // ceil(100000/128) buckets of 128 nodes
#define NCHUNK 512
#define CHUNK 2442        // ceil(1250000/512)
#define MAXE 4096         // per-round LDS edge capacity in bucket_gather2

typedef __attribute__((ext_vector_type(8))) short short8;
typedef __attribute__((ext_vector_type(8))) __bf16 bf16x8;
typedef __attribute__((ext_vector_type(4))) float f32x4;

static __device__ __forceinline__ short f2bf(float f) {
    union { float f; unsigned u; } v; v.f = f;
    unsigned r = (v.u + 0x7fffu + ((v.u >> 16) & 1u)) >> 16;
    return (short)r;
}
static __device__ __forceinline__ float bfu2f(unsigned u) {
    union { unsigned u; float f; } v; v.u = u << 16; return v.f;
}

// ---------------- W fragment prep ----------------
__global__ __launch_bounds__(256) void prep_w(const float* __restrict__ W1,
                                              const float* __restrict__ W2,
                                              short* __restrict__ wf) {
    int idx = blockIdx.x * 256 + threadIdx.x;   // 0..8191
    int layer = idx >> 12;
    int fi = idx & 4095;
    int fragidx = fi >> 9;
    int lane = (fi >> 3) & 63;
    int jj = fi & 7;
    int ct = fragidx >> 1, kt = fragidx & 1;
    int k = kt * 32 + (lane >> 4) * 8 + jj;
    int j = ct * 16 + (lane & 15);
    const float* W = layer ? W2 : W1;
    wf[idx] = f2bf(W[k * DIM + j]);
}

// ---------------- feat f32 -> bf16 ----------------
__global__ __launch_bounds__(256) void conv_feat(const float* __restrict__ f,
                                                 short* __restrict__ o) {
    int i = (blockIdx.x * 256 + threadIdx.x) * 8;   // grid exact: 6400000/8/256=3125
    float4 a = *(const float4*)(f + i);
    float4 b = *(const float4*)(f + i + 4);
    short8 t;
    t[0] = f2bf(a.x); t[1] = f2bf(a.y); t[2] = f2bf(a.z); t[3] = f2bf(a.w);
    t[4] = f2bf(b.x); t[5] = f2bf(b.y); t[6] = f2bf(b.z); t[7] = f2bf(b.w);
    *(short8*)(o + i) = t;
}

// ---------------- bucket partition ----------------
__global__ __launch_bounds__(256) void hist_chunks(const int* __restrict__ dst,
                                                   int* __restrict__ hist) {
    __shared__ int cnt[NB];
    for (int b = threadIdx.x; b < NB; b += 256) cnt[b] = 0;
    __syncthreads();
    int c = blockIdx.x;
    int base = c * CHUNK;
    int end = base + CHUNK; if (end > N_EDGES) end = N_EDGES;
    for (int i = base + threadIdx.x; i < end; i += 256)
        atomicAdd(&cnt[dst[i] >> 7], 1);
    __syncthreads();
    for (int b = threadIdx.x; b < NB; b += 256) hist[c * NB + b] = cnt[b];
}

// per-bucket running scan over chunks: hist[c][b] -> exclusive local offset; btot[b]=total
__global__ __launch_bounds__(64) void scan_cols(int* __restrict__ hist,
                                                int* __restrict__ btot) {
    int b = blockIdx.x * 64 + threadIdx.x;
    if (b >= NB) return;
    int run = 0;
#pragma unroll 8
    for (int c = 0; c < NCHUNK; ++c) {
        int t = hist[c * NB + b];
        hist[c * NB + b] = run;
        run += t;
    }
    btot[b] = run;
}

__global__ __launch_bounds__(1024) void scan_base(const int* __restrict__ btot,
                                                  int* __restrict__ bbase) {
    __shared__ int s[1024];
    int t = threadIdx.x;
    int v = (t < NB) ? btot[t] : 0;
    s[t] = v; __syncthreads();
    for (int off = 1; off < 1024; off <<= 1) {
        int u = (t >= off) ? s[t - off] : 0;
        __syncthreads();
        s[t] += u;
        __syncthreads();
    }
    if (t < NB) bbase[t] = s[t] - v;    // exclusive
}

// place edges: edgebuf[pos] = src | (dst&127)<<17, grouped by bucket
__global__ __launch_bounds__(256) void partition_edges(const int* __restrict__ src,
                                                       const int* __restrict__ dst,
                                                       const int* __restrict__ hist,
                                                       const int* __restrict__ bbase,
                                                       int* __restrict__ edgebuf) {
    __shared__ int cur[NB];
    int c = blockIdx.x;
    for (int b = threadIdx.x; b < NB; b += 256)
        cur[b] = bbase[b] + hist[c * NB + b];
    __syncthreads();
    int base = c * CHUNK;
    int end = base + CHUNK; if (end > N_EDGES) end = N_EDGES;
    for (int i = base + threadIdx.x; i < end; i += 256) {
        int d = dst[i];
        int b = d >> 7;
        int p = atomicAdd(&cur[b], 1);          // LDS return-atomic
        edgebuf[p] = src[i] | ((d & 127) << 17);
    }
}

// ---------------- per-bucket gather: in-LDS counting sort + register accumulation ----------------
// BF=1: featp is bf16 (row = 128 B = 16 uint2); BF=0: f32 (row = 256 B = 16 float4).
// 512 threads: 32 node-slots x 16 feature-lanes. acc[g][4] covers node g*32+slot.
template<int BF>
__global__ __launch_bounds__(512) void bucket_gather2(const int* __restrict__ bbase,
                                                      const int* __restrict__ btot,
                                                      const int* __restrict__ edgebuf,
                                                      const void* __restrict__ featp,
                                                      float* __restrict__ neigh) {
    __shared__ int ew[MAXE];        // 16 KB raw staged words
    __shared__ int es[MAXE];        // 16 KB node-sorted srcs
    __shared__ int cnt[128];
    __shared__ int offs[128];
    __shared__ int cur[128];

    int b = blockIdx.x;
    int node0 = b << 7;
    int eb = bbase[b], ec = btot[b];
    int tid = threadIdx.x;
    int c = tid & 15;               // feature chunk
    int slot = tid >> 4;            // 0..31

    float acc[4][4];
#pragma unroll
    for (int g = 0; g < 4; ++g)
#pragma unroll
        for (int j = 0; j < 4; ++j) acc[g][j] = 0.f;

    for (int r0 = 0; r0 < ec; r0 += MAXE) {
        int n = ec - r0; if (n > MAXE) n = MAXE;

        if (tid < 128) cnt[tid] = 0;
        __syncthreads();

        // stage + per-node count
        for (int i = tid; i < n; i += 512) {
            int w = edgebuf[eb + r0 + i];
            ew[i] = w;
            atomicAdd(&cnt[(w >> 17) & 127], 1);
        }
        __syncthreads();

        // exclusive scan of cnt[128] (Hillis-Steele in offs)
        if (tid < 128) offs[tid] = cnt[tid];
        __syncthreads();
        for (int d = 1; d < 128; d <<= 1) {
            int v = 0;
            if (tid < 128 && tid >= d) v = offs[tid - d];
            __syncthreads();
            if (tid < 128 && tid >= d) offs[tid] += v;
            __syncthreads();
        }
        if (tid < 128) {
            int x = offs[tid] - cnt[tid];   // exclusive
            offs[tid] = x;
            cur[tid] = x;
        }
        __syncthreads();

        // place: es grouped by local dst
        for (int i = tid; i < n; i += 512) {
            int w = ew[i];
            int p = atomicAdd(&cur[(w >> 17) & 127], 1);
            es[p] = w & 0x1FFFF;
        }
        __syncthreads();

        // segmented register gather
#pragma unroll
        for (int g = 0; g < 4; ++g) {
            int ld = g * 32 + slot;
            int s0 = offs[ld], s1 = s0 + cnt[ld];
            int i = s0;
            for (; i + 1 < s1; i += 2) {
                int sa = es[i], sb = es[i + 1];
                if (BF) {
                    uint2 pa = ((const uint2*)featp)[sa * 16 + c];
                    uint2 pb = ((const uint2*)featp)[sb * 16 + c];
                    acc[g][0] += bfu2f(pa.x & 0xffffu) + bfu2f(pb.x & 0xffffu);
                    acc[g][1] += bfu2f(pa.x >> 16)     + bfu2f(pb.x >> 16);
                    acc[g][2] += bfu2f(pa.y & 0xffffu) + bfu2f(pb.y & 0xffffu);
                    acc[g][3] += bfu2f(pa.y >> 16)     + bfu2f(pb.y >> 16);
                } else {
                    float4 va = ((const float4*)featp)[sa * 16 + c];
                    float4 vb = ((const float4*)featp)[sb * 16 + c];
                    acc[g][0] += va.x + vb.x;
                    acc[g][1] += va.y + vb.y;
                    acc[g][2] += va.z + vb.z;
                    acc[g][3] += va.w + vb.w;
                }
            }
            if (i < s1) {
                int sa = es[i];
                if (BF) {
                    uint2 pa = ((const uint2*)featp)[sa * 16 + c];
                    acc[g][0] += bfu2f(pa.x & 0xffffu);
                    acc[g][1] += bfu2f(pa.x >> 16);
                    acc[g][2] += bfu2f(pa.y & 0xffffu);
                    acc[g][3] += bfu2f(pa.y >> 16);
                } else {
                    float4 va = ((const float4*)featp)[sa * 16 + c];
                    acc[g][0] += va.x; acc[g][1] += va.y;
                    acc[g][2] += va.z; acc[g][3] += va.w;
                }
            }
        }
        __syncthreads();    // LDS reused next round
    }

    // write out
#pragma unroll
    for (int g = 0; g < 4; ++g) {
        int nodeg = node0 + g * 32 + slot;
        if (nodeg < N_NODES) {
            float4 v = { acc[g][0], acc[g][1], acc[g][2], acc[g][3] };
            ((float4*)neigh)[nodeg * 16 + c] = v;
        }
    }
}

// ---------------- fallback atomic scatter (tiny ws) ----------------
__global__ __launch_bounds__(256) void scatter_edges(const float4* __restrict__ feat4,
                                                     const int* __restrict__ src,
                                                     const int* __restrict__ dst,
                                                     float* __restrict__ neigh) {
    int idx = blockIdx.x * 256 + threadIdx.x;
    int e = idx >> 4, c = idx & 15;
    int s = src[e], d = dst[e];
    float4 v = feat4[s * 16 + c];
    float* p = neigh + d * 64 + c * 4;
    unsafeAtomicAdd(p + 0, v.x);
    unsafeAtomicAdd(p + 1, v.y);
    unsafeAtomicAdd(p + 2, v.z);
    unsafeAtomicAdd(p + 3, v.w);
}

// ---------------- fused combine + MLP ----------------
__global__ __launch_bounds__(256) void gin_mlp(const float* __restrict__ feat,
                                               float* __restrict__ neigh_out,
                                               const short* __restrict__ wf,
                                               const float* __restrict__ b1,
                                               const float* __restrict__ b2,
                                               const float* __restrict__ epsp) {
    __shared__ float hbuf[4][16][66];

    int lane = threadIdx.x & 63;
    int wv = threadIdx.x >> 6;
    int r = lane & 15, g = lane >> 4;
    int row0 = blockIdx.x * 64 + wv * 16;
    int node = row0 + r;
    bool valid = node < N_NODES;
    float epsv = 1.0f + epsp[0];

    const short8* w1f8 = (const short8*)(wf);
    const short8* w2f8 = (const short8*)(wf + 4096);

    short8 a[2];
    if (valid) {
        const float* fp = feat + node * 64 + g * 8;
        const float* np_ = neigh_out + node * 64 + g * 8;
#pragma unroll
        for (int kt = 0; kt < 2; ++kt) {
            float4 f0 = *(const float4*)(fp + kt * 32);
            float4 f1 = *(const float4*)(fp + kt * 32 + 4);
            float4 n0 = *(const float4*)(np_ + kt * 32);
            float4 n1 = *(const float4*)(np_ + kt * 32 + 4);
            float rs[8] = { epsv * f0.x + n0.x, epsv * f0.y + n0.y,
                            epsv * f0.z + n0.z, epsv * f0.w + n0.w,
                            epsv * f1.x + n1.x, epsv * f1.y + n1.y,
                            epsv * f1.z + n1.z, epsv * f1.w + n1.w };
            short8 t;
#pragma unroll
            for (int jj = 0; jj < 8; ++jj) t[jj] = f2bf(rs[jj]);
            a[kt] = t;
        }
    } else {
        short8 z = { 0, 0, 0, 0, 0, 0, 0, 0 };
        a[0] = z; a[1] = z;
    }

    f32x4 acc[4];
#pragma unroll
    for (int ct = 0; ct < 4; ++ct) {
        float bv = b1[ct * 16 + r];
        f32x4 c = { bv, bv, bv, bv };
        c = __builtin_amdgcn_mfma_f32_16x16x32_bf16(
                __builtin_bit_cast(bf16x8, a[0]),
                __builtin_bit_cast(bf16x8, w1f8[(ct * 2 + 0) * 64 + lane]),
                c, 0, 0, 0);
        c = __builtin_amdgcn_mfma_f32_16x16x32_bf16(
                __builtin_bit_cast(bf16x8, a[1]),
                __builtin_bit_cast(bf16x8, w1f8[(ct * 2 + 1) * 64 + lane]),
                c, 0, 0, 0);
        acc[ct] = c;
    }

#pragma unroll
    for (int ct = 0; ct < 4; ++ct)
#pragma unroll
        for (int i = 0; i < 4; ++i)
            hbuf[wv][g * 4 + i][ct * 16 + r] = fmaxf(acc[ct][i], 0.0f);

    __syncthreads();

    short8 a2[2];
#pragma unroll
    for (int kt = 0; kt < 2; ++kt) {
        const float2* hp = (const float2*)&hbuf[wv][r][kt * 32 + g * 8];
        float2 h0 = hp[0], h1 = hp[1], h2 = hp[2], h3 = hp[3];
        float hs[8] = { h0.x, h0.y, h1.x, h1.y, h2.x, h2.y, h3.x, h3.y };
        short8 t;
#pragma unroll
        for (int jj = 0; jj < 8; ++jj) t[jj] = f2bf(hs[jj]);
        a2[kt] = t;
    }

    f32x4 acc2[4];
#pragma unroll
    for (int ct = 0; ct < 4; ++ct) {
        float bv = b2[ct * 16 + r];
        f32x4 c = { bv, bv, bv, bv };
        c = __builtin_amdgcn_mfma_f32_16x16x32_bf16(
                __builtin_bit_cast(bf16x8, a2[0]),
                __builtin_bit_cast(bf16x8, w2f8[(ct * 2 + 0) * 64 + lane]),
                c, 0, 0, 0);
        c = __builtin_amdgcn_mfma_f32_16x16x32_bf16(
                __builtin_bit_cast(bf16x8, a2[1]),
                __builtin_bit_cast(bf16x8, w2f8[(ct * 2 + 1) * 64 + lane]),
                c, 0, 0, 0);
        acc2[ct] = c;
    }

#pragma unroll
    for (int ct = 0; ct < 4; ++ct)
#pragma unroll
        for (int i = 0; i < 4; ++i) {
            int nrow = row0 + g * 4 + i;
            if (nrow < N_NODES)
                neigh_out[nrow * 64 + ct * 16 + r] = acc2[ct][i];
        }
}

extern "C" void kernel_launch(void* const* d_in, const int* in_sizes, int n_in,
                              void* d_out, int out_size, void* d_ws, size_t ws_size,
                              hipStream_t stream) {
    const float* feat = (const float*)d_in[0];
    const float* W1   = (const float*)d_in[1];
    const float* b1   = (const float*)d_in[2];
    const float* W2   = (const float*)d_in[3];
    const float* b2   = (const float*)d_in[4];
    const float* eps  = (const float*)d_in[5];
    const int*   src  = (const int*)d_in[6];
    const int*   dst  = (const int*)d_in[7];
    float* out = (float*)d_out;

    char* ws = (char*)d_ws;
    short* wf = (short*)ws;                                     // 16384 B

    const size_t featbf_bytes = (size_t)N_NODES * DIM * 2;      // 12.8 MB
    const size_t hist_bytes   = (size_t)NCHUNK * NB * 4;        // 1.6 MB
    const size_t btot_bytes   = (size_t)NB * 4;
    const size_t edge_bytes   = (size_t)N_EDGES * 4;            // 5 MB
    const size_t need_mid  = 16384 + hist_bytes + 2 * btot_bytes + edge_bytes;
    const size_t need_full = need_mid + featbf_bytes;

    prep_w<<<32, 256, 0, stream>>>(W1, W2, wf);

    if (ws_size >= need_mid) {
        char* p = ws + 16384;
        short* featbf = nullptr;
        if (ws_size >= need_full) { featbf = (short*)p; p += featbf_bytes; }
        int* hist    = (int*)p;            p += hist_bytes;
        int* btot    = (int*)p;            p += btot_bytes;
        int* bbase   = (int*)p;            p += btot_bytes;
        int* edgebuf = (int*)p;

        if (featbf)
            conv_feat<<<3125, 256, 0, stream>>>(feat, featbf);

        hist_chunks<<<NCHUNK, 256, 0, stream>>>(dst, hist);
        scan_cols<<<(NB + 63) / 64, 64, 0, stream>>>(hist, btot);
        scan_base<<<1, 1024, 0, stream>>>(btot, bbase);
        partition_edges<<<NCHUNK, 256, 0, stream>>>(src, dst, hist, bbase, edgebuf);

        if (featbf)
            bucket_gather2<1><<<NB, 512, 0, stream>>>(bbase, btot, edgebuf, featbf, out);
        else
            bucket_gather2<0><<<NB, 512, 0, stream>>>(bbase, btot, edgebuf, feat, out);
    } else {
        hipMemsetAsync(d_out, 0, (size_t)N_NODES * DIM * sizeof(float), stream);
        scatter_edges<<<(N_EDGES * 16) / 256, 256, 0, stream>>>(
            (const float4*)feat, src, dst, out);
    }

    gin_mlp<<<(N_NODES + 63) / 64, 256, 0, stream>>>(feat, out, wf, b1, b2, eps);
}

// Round 6
// 100.145 us; speedup vs baseline: 1.1006x; 1.1006x over previous
//
#include <hip/hip_runtime.h>
#include <hip/hip_bf16.h>

#define N_NODES 100000
#define N_EDGES 1250000
#define DIM 64
#define NB 782            // ceil(100000/128) buckets of 128 nodes
#define NCHUNK 512
#define CHUNK 2442        // ceil(1250000/512)
#define MAXE 4096         // per-round LDS edge capacity in fused gather

typedef __attribute__((ext_vector_type(8))) short short8;
typedef __attribute__((ext_vector_type(8))) __bf16 bf16x8;
typedef __attribute__((ext_vector_type(4))) float f32x4;

static __device__ __forceinline__ short f2bf(float f) {
    union { float f; unsigned u; } v; v.f = f;
    unsigned r = (v.u + 0x7fffu + ((v.u >> 16) & 1u)) >> 16;
    return (short)r;
}
static __device__ __forceinline__ float bfu2f(unsigned u) {
    union { unsigned u; float f; } v; v.u = u << 16; return v.f;
}

// ---------------- prologue: conv_feat + prep_w + bucket counts in ONE kernel ----------------
// blocks [0, basePrep): feat f32->bf16 ; [basePrep, baseCnt): W fragments ;
// [baseCnt, baseCnt+NCHUNK): per-chunk LDS histogram -> global atomicAdd btot.
__global__ __launch_bounds__(256) void prologue(const float* __restrict__ feat,
                                                short* __restrict__ featbf,
                                                const float* __restrict__ W1,
                                                const float* __restrict__ W2,
                                                short* __restrict__ wf,
                                                const int* __restrict__ dst,
                                                int* __restrict__ btot,
                                                int basePrep, int baseCnt) {
    __shared__ int scnt[NB];
    int blk = blockIdx.x;
    if (blk < basePrep) {
        int i = (blk * 256 + threadIdx.x) * 8;
        float4 a = *(const float4*)(feat + i);
        float4 b = *(const float4*)(feat + i + 4);
        short8 t;
        t[0] = f2bf(a.x); t[1] = f2bf(a.y); t[2] = f2bf(a.z); t[3] = f2bf(a.w);
        t[4] = f2bf(b.x); t[5] = f2bf(b.y); t[6] = f2bf(b.z); t[7] = f2bf(b.w);
        *(short8*)(featbf + i) = t;
    } else if (blk < baseCnt) {
        int idx = (blk - basePrep) * 256 + threadIdx.x;   // 0..8191
        int layer = idx >> 12;
        int fi = idx & 4095;
        int fragidx = fi >> 9;
        int lane = (fi >> 3) & 63;
        int jj = fi & 7;
        int ct = fragidx >> 1, kt = fragidx & 1;
        int k = kt * 32 + (lane >> 4) * 8 + jj;
        int j = ct * 16 + (lane & 15);
        const float* W = layer ? W2 : W1;
        wf[idx] = f2bf(W[k * DIM + j]);
    } else {
        int c = blk - baseCnt;
        for (int b = threadIdx.x; b < NB; b += 256) scnt[b] = 0;
        __syncthreads();
        int base = c * CHUNK;
        int end = base + CHUNK; if (end > N_EDGES) end = N_EDGES;
        for (int i = base + threadIdx.x; i < end; i += 256)
            atomicAdd(&scnt[dst[i] >> 7], 1);
        __syncthreads();
        for (int b = threadIdx.x; b < NB; b += 256)
            if (scnt[b]) atomicAdd(&btot[b], scnt[b]);
    }
}

// ---------------- exclusive scan of btot[NB] -> bbase, cur ----------------
__global__ __launch_bounds__(1024) void scan_base(const int* __restrict__ btot,
                                                  int* __restrict__ bbase,
                                                  int* __restrict__ cur) {
    __shared__ int s[1024];
    int t = threadIdx.x;
    int v = (t < NB) ? btot[t] : 0;
    s[t] = v; __syncthreads();
    for (int off = 1; off < 1024; off <<= 1) {
        int u = (t >= off) ? s[t - off] : 0;
        __syncthreads();
        s[t] += u;
        __syncthreads();
    }
    if (t < NB) { int x = s[t] - v; bbase[t] = x; cur[t] = x; }
}

// ---------------- partition: per-block LDS count, range-reserve, place (unordered) ----------------
__global__ __launch_bounds__(256) void partition2(const int* __restrict__ src,
                                                  const int* __restrict__ dst,
                                                  int* __restrict__ cur,
                                                  int* __restrict__ edgebuf) {
    __shared__ int cnt[NB];
    __shared__ int lcur[NB];
    int c = blockIdx.x;
    int base = c * CHUNK;
    int end = base + CHUNK; if (end > N_EDGES) end = N_EDGES;

    for (int b = threadIdx.x; b < NB; b += 256) cnt[b] = 0;
    __syncthreads();
    for (int i = base + threadIdx.x; i < end; i += 256)
        atomicAdd(&cnt[dst[i] >> 7], 1);
    __syncthreads();
    for (int b = threadIdx.x; b < NB; b += 256)
        if (cnt[b]) lcur[b] = atomicAdd(&cur[b], cnt[b]);   // global return-atomic reserve
    __syncthreads();
    for (int i = base + threadIdx.x; i < end; i += 256) {
        int d = dst[i];
        int b = d >> 7;
        int p = atomicAdd(&lcur[b], 1);                     // LDS return-atomic
        edgebuf[p] = src[i] | ((d & 127) << 17);
    }
}

// ---------------- fused gather + combine + 2-layer MLP ----------------
// One block per 128-node bucket, 512 threads (8 waves).
// Phase 1: counting-sort edges in LDS, register-accumulate neigh (16 feat-lanes x 32 slots).
// Phase 2: neigh -> LDS tile; each wave does 16 rows of the MFMA MLP; write d_out.
template<int BF>
__global__ __launch_bounds__(512) void fused_gather_mlp(const int* __restrict__ bbase,
                                                        const int* __restrict__ btot,
                                                        const int* __restrict__ edgebuf,
                                                        const void* __restrict__ featp,
                                                        const float* __restrict__ feat,
                                                        const short* __restrict__ wf,
                                                        const float* __restrict__ b1,
                                                        const float* __restrict__ b2,
                                                        const float* __restrict__ epsp,
                                                        float* __restrict__ out) {
    __shared__ union {
        struct { int ew[MAXE]; int es[MAXE]; } s;   // 32 KB sort phase
        float tile[128][66];                        // 33792 B neigh tile / hbuf
    } u;
    __shared__ int cnt[128], offs[128], cur[128];

    int b = blockIdx.x;
    int node0 = b << 7;
    int eb = bbase[b], ec = btot[b];
    int tid = threadIdx.x;
    int c = tid & 15;               // feature chunk (4 floats)
    int slot = tid >> 4;            // 0..31

    float acc[4][4];
#pragma unroll
    for (int g = 0; g < 4; ++g)
#pragma unroll
        for (int j = 0; j < 4; ++j) acc[g][j] = 0.f;

    // ---------- phase 1: bucketed gather ----------
    for (int r0 = 0; r0 < ec; r0 += MAXE) {
        int n = ec - r0; if (n > MAXE) n = MAXE;

        if (tid < 128) cnt[tid] = 0;
        __syncthreads();

        for (int i = tid; i < n; i += 512) {
            int w = edgebuf[eb + r0 + i];
            u.s.ew[i] = w;
            atomicAdd(&cnt[(w >> 17) & 127], 1);
        }
        __syncthreads();

        if (tid < 128) offs[tid] = cnt[tid];
        __syncthreads();
        for (int d = 1; d < 128; d <<= 1) {
            int v = 0;
            if (tid < 128 && tid >= d) v = offs[tid - d];
            __syncthreads();
            if (tid < 128 && tid >= d) offs[tid] += v;
            __syncthreads();
        }
        if (tid < 128) {
            int x = offs[tid] - cnt[tid];
            offs[tid] = x;
            cur[tid] = x;
        }
        __syncthreads();

        for (int i = tid; i < n; i += 512) {
            int w = u.s.ew[i];
            int p = atomicAdd(&cur[(w >> 17) & 127], 1);
            u.s.es[p] = w & 0x1FFFF;
        }
        __syncthreads();

#pragma unroll
        for (int g = 0; g < 4; ++g) {
            int ld = g * 32 + slot;
            int s0 = offs[ld], s1 = s0 + cnt[ld];
            int i = s0;
            for (; i + 1 < s1; i += 2) {
                int sa = u.s.es[i], sb = u.s.es[i + 1];
                if (BF) {
                    uint2 pa = ((const uint2*)featp)[sa * 16 + c];
                    uint2 pb = ((const uint2*)featp)[sb * 16 + c];
                    acc[g][0] += bfu2f(pa.x & 0xffffu) + bfu2f(pb.x & 0xffffu);
                    acc[g][1] += bfu2f(pa.x >> 16)     + bfu2f(pb.x >> 16);
                    acc[g][2] += bfu2f(pa.y & 0xffffu) + bfu2f(pb.y & 0xffffu);
                    acc[g][3] += bfu2f(pa.y >> 16)     + bfu2f(pb.y >> 16);
                } else {
                    float4 va = ((const float4*)featp)[sa * 16 + c];
                    float4 vb = ((const float4*)featp)[sb * 16 + c];
                    acc[g][0] += va.x + vb.x;
                    acc[g][1] += va.y + vb.y;
                    acc[g][2] += va.z + vb.z;
                    acc[g][3] += va.w + vb.w;
                }
            }
            if (i < s1) {
                int sa = u.s.es[i];
                if (BF) {
                    uint2 pa = ((const uint2*)featp)[sa * 16 + c];
                    acc[g][0] += bfu2f(pa.x & 0xffffu);
                    acc[g][1] += bfu2f(pa.x >> 16);
                    acc[g][2] += bfu2f(pa.y & 0xffffu);
                    acc[g][3] += bfu2f(pa.y >> 16);
                } else {
                    float4 va = ((const float4*)featp)[sa * 16 + c];
                    acc[g][0] += va.x; acc[g][1] += va.y;
                    acc[g][2] += va.z; acc[g][3] += va.w;
                }
            }
        }
        __syncthreads();
    }
    __syncthreads();

    // ---------- phase 2: neigh -> LDS tile (stride 66) ----------
#pragma unroll
    for (int g = 0; g < 4; ++g) {
        int ld = g * 32 + slot;
#pragma unroll
        for (int j = 0; j < 4; ++j)
            u.tile[ld][c * 4 + j] = acc[g][j];
    }
    __syncthreads();

    // ---------- phase 3: MLP, one wave per 16 rows ----------
    int wv = tid >> 6;
    int lane = tid & 63;
    int r = lane & 15, gg = lane >> 4;
    int row = wv * 16 + r;              // local row 0..127
    int node = node0 + row;
    bool valid = node < N_NODES;
    float epsv = 1.0f + epsp[0];

    const short8* w1f8 = (const short8*)(wf);
    const short8* w2f8 = (const short8*)(wf + 4096);

    short8 a[2];
    {
        const float* fp = feat + (size_t)node * 64 + gg * 8;
#pragma unroll
        for (int kt = 0; kt < 2; ++kt) {
            float f0x=0,f0y=0,f0z=0,f0w=0,f1x=0,f1y=0,f1z=0,f1w=0;
            if (valid) {
                float4 f0 = *(const float4*)(fp + kt * 32);
                float4 f1 = *(const float4*)(fp + kt * 32 + 4);
                f0x=f0.x; f0y=f0.y; f0z=f0.z; f0w=f0.w;
                f1x=f1.x; f1y=f1.y; f1z=f1.z; f1w=f1.w;
            }
            const float2* tp = (const float2*)&u.tile[row][kt * 32 + gg * 8];
            float2 n0 = tp[0], n1 = tp[1], n2 = tp[2], n3 = tp[3];
            float rs[8] = { epsv * f0x + n0.x, epsv * f0y + n0.y,
                            epsv * f0z + n1.x, epsv * f0w + n1.y,
                            epsv * f1x + n2.x, epsv * f1y + n2.y,
                            epsv * f1z + n3.x, epsv * f1w + n3.y };
            short8 t;
#pragma unroll
            for (int jj = 0; jj < 8; ++jj) t[jj] = f2bf(rs[jj]);
            a[kt] = t;
        }
    }
    __syncthreads();    // all tile reads done before hbuf overwrite

    f32x4 acc1[4];
#pragma unroll
    for (int ct = 0; ct < 4; ++ct) {
        float bv = b1[ct * 16 + r];
        f32x4 cc = { bv, bv, bv, bv };
        cc = __builtin_amdgcn_mfma_f32_16x16x32_bf16(
                __builtin_bit_cast(bf16x8, a[0]),
                __builtin_bit_cast(bf16x8, w1f8[(ct * 2 + 0) * 64 + lane]),
                cc, 0, 0, 0);
        cc = __builtin_amdgcn_mfma_f32_16x16x32_bf16(
                __builtin_bit_cast(bf16x8, a[1]),
                __builtin_bit_cast(bf16x8, w1f8[(ct * 2 + 1) * 64 + lane]),
                cc, 0, 0, 0);
        acc1[ct] = cc;
    }

    // relu + transpose h through LDS (hbuf aliases tile region; per-wave slice)
#pragma unroll
    for (int ct = 0; ct < 4; ++ct)
#pragma unroll
        for (int i = 0; i < 4; ++i)
            u.tile[wv * 16 + gg * 4 + i][ct * 16 + r] = fmaxf(acc1[ct][i], 0.0f);
    __syncthreads();

    short8 a2[2];
#pragma unroll
    for (int kt = 0; kt < 2; ++kt) {
        const float2* hp = (const float2*)&u.tile[wv * 16 + r][kt * 32 + gg * 8];
        float2 h0 = hp[0], h1 = hp[1], h2 = hp[2], h3 = hp[3];
        float hs[8] = { h0.x, h0.y, h1.x, h1.y, h2.x, h2.y, h3.x, h3.y };
        short8 t;
#pragma unroll
        for (int jj = 0; jj < 8; ++jj) t[jj] = f2bf(hs[jj]);
        a2[kt] = t;
    }

    f32x4 acc2[4];
#pragma unroll
    for (int ct = 0; ct < 4; ++ct) {
        float bv = b2[ct * 16 + r];
        f32x4 cc = { bv, bv, bv, bv };
        cc = __builtin_amdgcn_mfma_f32_16x16x32_bf16(
                __builtin_bit_cast(bf16x8, a2[0]),
                __builtin_bit_cast(bf16x8, w2f8[(ct * 2 + 0) * 64 + lane]),
                cc, 0, 0, 0);
        cc = __builtin_amdgcn_mfma_f32_16x16x32_bf16(
                __builtin_bit_cast(bf16x8, a2[1]),
                __builtin_bit_cast(bf16x8, w2f8[(ct * 2 + 1) * 64 + lane]),
                cc, 0, 0, 0);
        acc2[ct] = cc;
    }

#pragma unroll
    for (int ct = 0; ct < 4; ++ct)
#pragma unroll
        for (int i = 0; i < 4; ++i) {
            int nrow = node0 + wv * 16 + gg * 4 + i;
            if (nrow < N_NODES)
                out[(size_t)nrow * 64 + ct * 16 + r] = acc2[ct][i];
        }
}

// ---------------- tiny-ws fallback: atomic scatter + separate MLP ----------------
__global__ __launch_bounds__(256) void scatter_edges(const float4* __restrict__ feat4,
                                                     const int* __restrict__ src,
                                                     const int* __restrict__ dst,
                                                     float* __restrict__ neigh) {
    int idx = blockIdx.x * 256 + threadIdx.x;
    int e = idx >> 4, c = idx & 15;
    int s = src[e], d = dst[e];
    float4 v = feat4[s * 16 + c];
    float* p = neigh + d * 64 + c * 4;
    unsafeAtomicAdd(p + 0, v.x);
    unsafeAtomicAdd(p + 1, v.y);
    unsafeAtomicAdd(p + 2, v.z);
    unsafeAtomicAdd(p + 3, v.w);
}

__global__ __launch_bounds__(256) void prep_w(const float* __restrict__ W1,
                                              const float* __restrict__ W2,
                                              short* __restrict__ wf) {
    int idx = blockIdx.x * 256 + threadIdx.x;
    int layer = idx >> 12;
    int fi = idx & 4095;
    int fragidx = fi >> 9;
    int lane = (fi >> 3) & 63;
    int jj = fi & 7;
    int ct = fragidx >> 1, kt = fragidx & 1;
    int k = kt * 32 + (lane >> 4) * 8 + jj;
    int j = ct * 16 + (lane & 15);
    const float* W = layer ? W2 : W1;
    wf[idx] = f2bf(W[k * DIM + j]);
}

__global__ __launch_bounds__(256) void gin_mlp(const float* __restrict__ feat,
                                               float* __restrict__ neigh_out,
                                               const short* __restrict__ wf,
                                               const float* __restrict__ b1,
                                               const float* __restrict__ b2,
                                               const float* __restrict__ epsp) {
    __shared__ float hbuf[4][16][66];
    int lane = threadIdx.x & 63;
    int wv = threadIdx.x >> 6;
    int r = lane & 15, g = lane >> 4;
    int row0 = blockIdx.x * 64 + wv * 16;
    int node = row0 + r;
    bool valid = node < N_NODES;
    float epsv = 1.0f + epsp[0];
    const short8* w1f8 = (const short8*)(wf);
    const short8* w2f8 = (const short8*)(wf + 4096);
    short8 a[2];
    if (valid) {
        const float* fp = feat + node * 64 + g * 8;
        const float* np_ = neigh_out + node * 64 + g * 8;
#pragma unroll
        for (int kt = 0; kt < 2; ++kt) {
            float4 f0 = *(const float4*)(fp + kt * 32);
            float4 f1 = *(const float4*)(fp + kt * 32 + 4);
            float4 n0 = *(const float4*)(np_ + kt * 32);
            float4 n1 = *(const float4*)(np_ + kt * 32 + 4);
            float rs[8] = { epsv * f0.x + n0.x, epsv * f0.y + n0.y,
                            epsv * f0.z + n0.z, epsv * f0.w + n0.w,
                            epsv * f1.x + n1.x, epsv * f1.y + n1.y,
                            epsv * f1.z + n1.z, epsv * f1.w + n1.w };
            short8 t;
#pragma unroll
            for (int jj = 0; jj < 8; ++jj) t[jj] = f2bf(rs[jj]);
            a[kt] = t;
        }
    } else {
        short8 z = { 0,0,0,0,0,0,0,0 };
        a[0] = z; a[1] = z;
    }
    f32x4 acc[4];
#pragma unroll
    for (int ct = 0; ct < 4; ++ct) {
        float bv = b1[ct * 16 + r];
        f32x4 c = { bv, bv, bv, bv };
        c = __builtin_amdgcn_mfma_f32_16x16x32_bf16(
                __builtin_bit_cast(bf16x8, a[0]),
                __builtin_bit_cast(bf16x8, w1f8[(ct * 2 + 0) * 64 + lane]), c, 0, 0, 0);
        c = __builtin_amdgcn_mfma_f32_16x16x32_bf16(
                __builtin_bit_cast(bf16x8, a[1]),
                __builtin_bit_cast(bf16x8, w1f8[(ct * 2 + 1) * 64 + lane]), c, 0, 0, 0);
        acc[ct] = c;
    }
#pragma unroll
    for (int ct = 0; ct < 4; ++ct)
#pragma unroll
        for (int i = 0; i < 4; ++i)
            hbuf[wv][g * 4 + i][ct * 16 + r] = fmaxf(acc[ct][i], 0.0f);
    __syncthreads();
    short8 a2[2];
#pragma unroll
    for (int kt = 0; kt < 2; ++kt) {
        const float2* hp = (const float2*)&hbuf[wv][r][kt * 32 + g * 8];
        float2 h0 = hp[0], h1 = hp[1], h2 = hp[2], h3 = hp[3];
        float hs[8] = { h0.x, h0.y, h1.x, h1.y, h2.x, h2.y, h3.x, h3.y };
        short8 t;
#pragma unroll
        for (int jj = 0; jj < 8; ++jj) t[jj] = f2bf(hs[jj]);
        a2[kt] = t;
    }
    f32x4 acc2[4];
#pragma unroll
    for (int ct = 0; ct < 4; ++ct) {
        float bv = b2[ct * 16 + r];
        f32x4 c = { bv, bv, bv, bv };
        c = __builtin_amdgcn_mfma_f32_16x16x32_bf16(
                __builtin_bit_cast(bf16x8, a2[0]),
                __builtin_bit_cast(bf16x8, w2f8[(ct * 2 + 0) * 64 + lane]), c, 0, 0, 0);
        c = __builtin_amdgcn_mfma_f32_16x16x32_bf16(
                __builtin_bit_cast(bf16x8, a2[1]),
                __builtin_bit_cast(bf16x8, w2f8[(ct * 2 + 1) * 64 + lane]), c, 0, 0, 0);
        acc2[ct] = c;
    }
#pragma unroll
    for (int ct = 0; ct < 4; ++ct)
#pragma unroll
        for (int i = 0; i < 4; ++i) {
            int nrow = row0 + g * 4 + i;
            if (nrow < N_NODES)
                neigh_out[nrow * 64 + ct * 16 + r] = acc2[ct][i];
        }
}

extern "C" void kernel_launch(void* const* d_in, const int* in_sizes, int n_in,
                              void* d_out, int out_size, void* d_ws, size_t ws_size,
                              hipStream_t stream) {
    const float* feat = (const float*)d_in[0];
    const float* W1   = (const float*)d_in[1];
    const float* b1   = (const float*)d_in[2];
    const float* W2   = (const float*)d_in[3];
    const float* b2   = (const float*)d_in[4];
    const float* eps  = (const float*)d_in[5];
    const int*   src  = (const int*)d_in[6];
    const int*   dst  = (const int*)d_in[7];
    float* out = (float*)d_out;

    char* ws = (char*)d_ws;
    short* wf = (short*)ws;                                     // 16384 B

    const size_t featbf_bytes = (size_t)N_NODES * DIM * 2;      // 12.8 MB
    const size_t btot_bytes   = (size_t)NB * 4;
    const size_t edge_bytes   = (size_t)N_EDGES * 4;            // 5 MB
    const size_t need_mid  = 16384 + 3 * btot_bytes + edge_bytes;
    const size_t need_full = need_mid + featbf_bytes;

    if (ws_size >= need_mid) {
        char* p = ws + 16384;
        short* featbf = nullptr;
        if (ws_size >= need_full) { featbf = (short*)p; p += featbf_bytes; }
        int* btot    = (int*)p;            p += btot_bytes;
        int* bbase   = (int*)p;            p += btot_bytes;
        int* cur     = (int*)p;            p += btot_bytes;
        int* edgebuf = (int*)p;

        hipMemsetAsync(btot, 0, btot_bytes, stream);

        int nConv = featbf ? 3125 : 0;          // 6.4M floats / (256*8)
        int basePrep = nConv;
        int baseCnt  = nConv + 32;              // prep_w: 8192 / 256
        prologue<<<baseCnt + NCHUNK, 256, 0, stream>>>(
            feat, featbf, W1, W2, wf, dst, btot, basePrep, baseCnt);

        scan_base<<<1, 1024, 0, stream>>>(btot, bbase, cur);
        partition2<<<NCHUNK, 256, 0, stream>>>(src, dst, cur, edgebuf);

        if (featbf)
            fused_gather_mlp<1><<<NB, 512, 0, stream>>>(
                bbase, btot, edgebuf, featbf, feat, wf, b1, b2, eps, out);
        else
            fused_gather_mlp<0><<<NB, 512, 0, stream>>>(
                bbase, btot, edgebuf, feat, feat, wf, b1, b2, eps, out);
    } else {
        prep_w<<<32, 256, 0, stream>>>(W1, W2, wf);
        hipMemsetAsync(d_out, 0, (size_t)N_NODES * DIM * sizeof(float), stream);
        scatter_edges<<<(N_EDGES * 16) / 256, 256, 0, stream>>>(
            (const float4*)feat, src, dst, out);
        gin_mlp<<<(N_NODES + 63) / 64, 256, 0, stream>>>(feat, out, wf, b1, b2, eps);
    }
}